// Round 5
// baseline (144.385 us; speedup 1.0000x reference)
//
#include <hip/hip_runtime.h>

#define BLOCK 512   // 8 waves
#define GRID  512   // 2 blocks/CU, grid-stride over tiles
#define NW    (GRID * 8)

typedef __attribute__((ext_vector_type(8))) short short8;   // 8 x bf16
typedef __attribute__((ext_vector_type(4))) float f32x4;    // MFMA C/D frag

__device__ __forceinline__ unsigned short f2bf(float f) {
    unsigned u = __builtin_bit_cast(unsigned, f);
    u += 0x7FFFu + ((u >> 16) & 1u);
    return (unsigned short)(u >> 16);
}

__device__ __forceinline__ unsigned pkbf(float lo, float hi) {
    // dst[15:0]=bf16(lo), dst[31:16]=bf16(hi), RNE
    unsigned r;
    asm("v_cvt_pk_bf16_f32 %0, %1, %2" : "=v"(r) : "v"(lo), "v"(hi));
    return r;
}

__device__ __forceinline__ float fast_tanh(float v) {
    // tanh(v) = 1 - 2/(1 + 2^(v * 2*log2(e))); exact at +-inf
    float e = __builtin_amdgcn_exp2f(v * 2.8853900817779268f);
    return 1.0f - 2.0f * __builtin_amdgcn_rcpf(1.0f + e);
}

// LayerNorm + tanh, transposed layout: lane holds edge `cl`, h-cols m*16+kg*4+i.
#define LN_T(PB, PG, PT, A)                                                   \
    {                                                                         \
        float s = 0.f, q = 0.f;                                               \
        _Pragma("unroll")                                                     \
        for (int m = 0; m < 4; ++m) {                                         \
            const float4 pb = *reinterpret_cast<const float4*>(               \
                plds + (PB) * 64 + m * 16 + kg * 4);                          \
            A[m][0] += pb.x; A[m][1] += pb.y;                                 \
            A[m][2] += pb.z; A[m][3] += pb.w;                                 \
            s += (A[m][0] + A[m][1]) + (A[m][2] + A[m][3]);                   \
            q = fmaf(A[m][0], A[m][0], q); q = fmaf(A[m][1], A[m][1], q);     \
            q = fmaf(A[m][2], A[m][2], q); q = fmaf(A[m][3], A[m][3], q);     \
        }                                                                     \
        s += __shfl_xor(s, 16); s += __shfl_xor(s, 32);                       \
        q += __shfl_xor(q, 16); q += __shfl_xor(q, 32);                       \
        const float mu = s * 0.015625f;                                       \
        float var = fmaf(q, 0.015625f, -mu * mu);                             \
        var = fmaxf(var, 0.0f);                                               \
        const float rs = __builtin_amdgcn_rsqf(var + 1e-5f);                  \
        const float mrs = mu * rs;                                            \
        _Pragma("unroll")                                                     \
        for (int m = 0; m < 4; ++m) {                                         \
            const float4 pg = *reinterpret_cast<const float4*>(               \
                plds + (PG) * 64 + m * 16 + kg * 4);                          \
            const float4 pt = *reinterpret_cast<const float4*>(               \
                plds + (PT) * 64 + m * 16 + kg * 4);                          \
            A[m][0] = fast_tanh(fmaf(fmaf(A[m][0], rs, -mrs), pg.x, pt.x));   \
            A[m][1] = fast_tanh(fmaf(fmaf(A[m][1], rs, -mrs), pg.y, pt.y));   \
            A[m][2] = fast_tanh(fmaf(fmaf(A[m][2], rs, -mrs), pg.z, pt.z));   \
            A[m][3] = fast_tanh(fmaf(fmaf(A[m][3], rs, -mrs), pg.w, pt.w));   \
        }                                                                     \
    }

#define H_STORE_T(A)                                                          \
    _Pragma("unroll")                                                         \
    for (int m = 0; m < 4; ++m) {                                             \
        uint2 u;                                                              \
        u.x = pkbf(A[m][0], A[m][1]);                                         \
        u.y = pkbf(A[m][2], A[m][3]);                                         \
        *reinterpret_cast<uint2*>(hwv + cl * 72 + m * 16 + kg * 4) = u;       \
    }

template<bool PREBF>
__global__ __launch_bounds__(BLOCK, 4) void edge_mlp_t(
    const void* __restrict__ xsrc, const int* __restrict__ ei,
    const float* __restrict__ W1, const float* __restrict__ b1,
    const float* __restrict__ g1, const float* __restrict__ bt1,
    const float* __restrict__ W2, const float* __restrict__ b2,
    const float* __restrict__ g2, const float* __restrict__ bt2,
    const float* __restrict__ W3, const float* __restrict__ b3,
    const float* __restrict__ g3, const float* __restrict__ bt3,
    const float* __restrict__ W4, const float* __restrict__ b4,
    float* __restrict__ out, int E)
{
    __shared__ unsigned short wlds[32 * 512];          // 32 KiB W^T frags
    __shared__ unsigned short hlds[8 * 16 * 72];       // per-wave [16 edge][72] bf16
    __shared__ float plds[10 * 64];                    // b,g,bt x3 + W4

    const int tid  = threadIdx.x;
    const int widx = tid >> 6;
    const int lane = tid & 63;
    const int kg   = lane >> 4;   // 0..3
    const int cl   = lane & 15;   // 0..15 = edge within tile

    for (int fi = widx; fi < 32; fi += 8) {
        const float* Wsrc; int m, kb;
        if (fi < 16) { Wsrc = W1; m = fi >> 2; kb = fi & 3; }
        else { int f = fi - 16; Wsrc = (f < 8) ? W2 : W3; f &= 7; m = f >> 1; kb = f & 1; }
        const float* src = Wsrc + (size_t)(kb * 32 + kg * 8) * 64 + m * 16 + cl;
        short8 pk8;
        #pragma unroll
        for (int j = 0; j < 8; ++j) pk8[j] = (short)f2bf(src[j * 64]);
        *reinterpret_cast<short8*>(&wlds[fi * 512 + lane * 8]) = pk8;
    }
    for (int i = tid; i < 640; i += BLOCK) {   // grid-stride: BLOCK < 640
        const int p = i >> 6, c = i & 63;
        const float* sp;
        switch (p) {
            case 0: sp = b1;  break; case 1: sp = g1;  break; case 2: sp = bt1; break;
            case 3: sp = b2;  break; case 4: sp = g2;  break; case 5: sp = bt2; break;
            case 6: sp = b3;  break; case 7: sp = g3;  break; case 8: sp = bt3; break;
            default: sp = W4; break;
        }
        plds[i] = sp[c];
    }
    const float b4s = b4[0];
    __syncthreads();

    const unsigned short* xb = (const unsigned short*)xsrc;
    const float*          xf = (const float*)xsrc;
    unsigned short* hwv = hlds + widx * (16 * 72);

    const int ntiles = (E + 15) >> 4;

    // ---- 2-deep pipeline state ----
    short8 xa[4];      // PREBF: x data for current tile
    float4 uraw[8];    // !PREBF: raw f32 x data for current tile
    int ns1, ne1;      // node indices for tile t+NW

    auto ldidx = [&](int tp, int& a, int& b) {
        const int tpc = min(tp, ntiles - 1);
        const int er  = min((tpc << 4) + cl, E - 1);
        a = ei[er]; b = ei[E + er];
    };
    auto ldx = [&](int a, int b) {
        #pragma unroll
        for (int kb = 0; kb < 4; ++kb) {
            const size_t off = (size_t)(kb < 2 ? a : b) * 64 + (kb & 1) * 32 + kg * 8;
            if constexpr (PREBF) {
                xa[kb] = *reinterpret_cast<const short8*>(xb + off);
            } else {
                uraw[2 * kb]     = *reinterpret_cast<const float4*>(xf + off);
                uraw[2 * kb + 1] = *reinterpret_cast<const float4*>(xf + off + 4);
            }
        }
    };

    int t = (int)blockIdx.x * 8 + widx;
    {   // prologue: tile t data + tile t+NW indices in flight
        int ns0, ne0;
        ldidx(t, ns0, ne0);
        ldx(ns0, ne0);
        ldidx(t + NW, ns1, ne1);
    }

    for (; t < ntiles; t += NW) {
        // ---- consume current tile's loads (issued a full tile ago) ----
        short8 cur[4];
        if constexpr (PREBF) {
            #pragma unroll
            for (int kb = 0; kb < 4; ++kb) cur[kb] = xa[kb];
        } else {
            #pragma unroll
            for (int kb = 0; kb < 4; ++kb) {
                uint4 tp_;
                tp_.x = pkbf(uraw[2 * kb].x,     uraw[2 * kb].y);
                tp_.y = pkbf(uraw[2 * kb].z,     uraw[2 * kb].w);
                tp_.z = pkbf(uraw[2 * kb + 1].x, uraw[2 * kb + 1].y);
                tp_.w = pkbf(uraw[2 * kb + 1].z, uraw[2 * kb + 1].w);
                cur[kb] = __builtin_bit_cast(short8, tp_);
            }
        }
        // ---- issue next tile's x loads + next-next indices ----
        ldx(ns1, ne1);
        ldidx(t + 2 * NW, ns1, ne1);

        // ---------- Layer 1 ----------
        f32x4 acc[4] = {{0,0,0,0},{0,0,0,0},{0,0,0,0},{0,0,0,0}};
        #pragma unroll
        for (int kb = 0; kb < 4; ++kb) {
            #pragma unroll
            for (int m = 0; m < 4; ++m) {
                const short8 wf = *reinterpret_cast<const short8*>(
                    &wlds[(m * 4 + kb) * 512 + lane * 8]);
                acc[m] = __builtin_amdgcn_mfma_f32_16x16x32_bf16(wf, cur[kb], acc[m], 0, 0, 0);
            }
        }
        LN_T(0, 1, 2, acc);
        H_STORE_T(acc);

        // ---------- Layer 2 ----------
        f32x4 acc2[4] = {{0,0,0,0},{0,0,0,0},{0,0,0,0},{0,0,0,0}};
        #pragma unroll
        for (int kb = 0; kb < 2; ++kb) {
            const short8 hf = *reinterpret_cast<const short8*>(
                hwv + cl * 72 + kb * 32 + kg * 8);
            #pragma unroll
            for (int m = 0; m < 4; ++m) {
                const short8 wf = *reinterpret_cast<const short8*>(
                    &wlds[(16 + m * 2 + kb) * 512 + lane * 8]);
                acc2[m] = __builtin_amdgcn_mfma_f32_16x16x32_bf16(wf, hf, acc2[m], 0, 0, 0);
            }
        }
        LN_T(3, 4, 5, acc2);
        H_STORE_T(acc2);

        // ---------- Layer 3 ----------
        f32x4 acc3[4] = {{0,0,0,0},{0,0,0,0},{0,0,0,0},{0,0,0,0}};
        #pragma unroll
        for (int kb = 0; kb < 2; ++kb) {
            const short8 hf = *reinterpret_cast<const short8*>(
                hwv + cl * 72 + kb * 32 + kg * 8);
            #pragma unroll
            for (int m = 0; m < 4; ++m) {
                const short8 wf = *reinterpret_cast<const short8*>(
                    &wlds[(24 + m * 2 + kb) * 512 + lane * 8]);
                acc3[m] = __builtin_amdgcn_mfma_f32_16x16x32_bf16(wf, hf, acc3[m], 0, 0, 0);
            }
        }
        LN_T(6, 7, 8, acc3);

        // ---------- Layer 4 ----------
        float p = 0.f;
        #pragma unroll
        for (int m = 0; m < 4; ++m) {
            const float4 w4 = *reinterpret_cast<const float4*>(
                plds + 9 * 64 + m * 16 + kg * 4);
            p = fmaf(acc3[m][0], w4.x, p); p = fmaf(acc3[m][1], w4.y, p);
            p = fmaf(acc3[m][2], w4.z, p); p = fmaf(acc3[m][3], w4.w, p);
        }
        p += __shfl_xor(p, 16); p += __shfl_xor(p, 32);
        if (kg == 0) {
            const int e = (t << 4) + cl;
            if (e < E) {
                const float o = p + b4s;
                // sigmoid(o) = 1/(1 + 2^(-o*log2(e)))
                out[e] = __builtin_amdgcn_rcpf(
                    1.0f + __builtin_amdgcn_exp2f(o * -1.4426950408889634f));
            }
        }
    }
}

__global__ __launch_bounds__(256) void cvt_x_bf16(const float* __restrict__ x,
                                                  unsigned short* __restrict__ xbf,
                                                  int n) {
    const int i = (blockIdx.x * 256 + threadIdx.x) * 8;
    if (i >= n) return;
    const float4 u0 = *reinterpret_cast<const float4*>(x + i);
    const float4 u1 = *reinterpret_cast<const float4*>(x + i + 4);
    uint4 t;
    t.x = pkbf(u0.x, u0.y); t.y = pkbf(u0.z, u0.w);
    t.z = pkbf(u1.x, u1.y); t.w = pkbf(u1.z, u1.w);
    *reinterpret_cast<uint4*>(xbf + i) = t;
}

extern "C" void kernel_launch(void* const* d_in, const int* in_sizes, int n_in,
                              void* d_out, int out_size, void* d_ws, size_t ws_size,
                              hipStream_t stream) {
    const float* x   = (const float*)d_in[0];
    const int*   ei  = (const int*)  d_in[1];
    const float* W1  = (const float*)d_in[2];
    const float* b1  = (const float*)d_in[3];
    const float* g1  = (const float*)d_in[4];
    const float* bt1 = (const float*)d_in[5];
    const float* W2  = (const float*)d_in[6];
    const float* b2  = (const float*)d_in[7];
    const float* g2  = (const float*)d_in[8];
    const float* bt2 = (const float*)d_in[9];
    const float* W3  = (const float*)d_in[10];
    const float* b3  = (const float*)d_in[11];
    const float* g3  = (const float*)d_in[12];
    const float* bt3 = (const float*)d_in[13];
    const float* W4  = (const float*)d_in[14];
    const float* b4  = (const float*)d_in[15];
    float* out = (float*)d_out;

    const int E  = in_sizes[1] / 2;
    const int nX = in_sizes[0];                 // n_nodes * 64

    if (ws_size >= (size_t)nX * 2) {
        unsigned short* xbf = (unsigned short*)d_ws;
        const int grid_c = (nX / 8 + 255) / 256;
        hipLaunchKernelGGL(cvt_x_bf16, dim3(grid_c), dim3(256), 0, stream, x, xbf, nX);
        hipLaunchKernelGGL((edge_mlp_t<true>), dim3(GRID), dim3(BLOCK), 0, stream,
                           (const void*)xbf, ei, W1, b1, g1, bt1, W2, b2, g2, bt2,
                           W3, b3, g3, bt3, W4, b4, out, E);
    } else {
        hipLaunchKernelGGL((edge_mlp_t<false>), dim3(GRID), dim3(BLOCK), 0, stream,
                           (const void*)x, ei, W1, b1, g1, bt1, W2, b2, g2, bt2,
                           W3, b3, g3, bt3, W4, b4, out, E);
    }
}

// Round 6
// 119.824 us; speedup vs baseline: 1.2050x; 1.2050x over previous
//
#include <hip/hip_runtime.h>

#define BLOCK 512   // 8 waves

typedef __attribute__((ext_vector_type(8))) short short8;   // 8 x bf16
typedef __attribute__((ext_vector_type(4))) float f32x4;    // MFMA C/D frag

__device__ __forceinline__ unsigned short f2bf(float f) {
    unsigned u = __builtin_bit_cast(unsigned, f);
    u += 0x7FFFu + ((u >> 16) & 1u);
    return (unsigned short)(u >> 16);
}

__device__ __forceinline__ unsigned pkbf(float lo, float hi) {
    // dst[15:0]=bf16(lo), dst[31:16]=bf16(hi), RNE
    unsigned r;
    asm("v_cvt_pk_bf16_f32 %0, %1, %2" : "=v"(r) : "v"(lo), "v"(hi));
    return r;
}

__device__ __forceinline__ float fast_tanh(float v) {
    // tanh(v) = 1 - 2/(1 + 2^(v * 2*log2(e))); exact at +-inf
    float e = __builtin_amdgcn_exp2f(v * 2.8853900817779268f);
    return 1.0f - 2.0f * __builtin_amdgcn_rcpf(1.0f + e);
}

// LayerNorm + tanh, transposed layout: lane holds edge `cl`, h-cols m*16+kg*4+i.
#define LN_T(PB, PG, PT, A)                                                   \
    {                                                                         \
        float s = 0.f, q = 0.f;                                               \
        _Pragma("unroll")                                                     \
        for (int m = 0; m < 4; ++m) {                                         \
            const float4 pb = *reinterpret_cast<const float4*>(               \
                plds + (PB) * 64 + m * 16 + kg4);                             \
            A[m][0] += pb.x; A[m][1] += pb.y;                                 \
            A[m][2] += pb.z; A[m][3] += pb.w;                                 \
            s += (A[m][0] + A[m][1]) + (A[m][2] + A[m][3]);                   \
            q = fmaf(A[m][0], A[m][0], q); q = fmaf(A[m][1], A[m][1], q);     \
            q = fmaf(A[m][2], A[m][2], q); q = fmaf(A[m][3], A[m][3], q);     \
        }                                                                     \
        s += __shfl_xor(s, 16); s += __shfl_xor(s, 32);                       \
        q += __shfl_xor(q, 16); q += __shfl_xor(q, 32);                       \
        const float mu = s * 0.015625f;                                       \
        float var = fmaf(q, 0.015625f, -mu * mu);                             \
        var = fmaxf(var, 0.0f);                                               \
        const float rs = __builtin_amdgcn_rsqf(var + 1e-5f);                  \
        const float mrs = mu * rs;                                            \
        _Pragma("unroll")                                                     \
        for (int m = 0; m < 4; ++m) {                                         \
            const float4 pg = *reinterpret_cast<const float4*>(               \
                plds + (PG) * 64 + m * 16 + kg4);                             \
            const float4 pt = *reinterpret_cast<const float4*>(               \
                plds + (PT) * 64 + m * 16 + kg4);                             \
            A[m][0] = fast_tanh(fmaf(fmaf(A[m][0], rs, -mrs), pg.x, pt.x));   \
            A[m][1] = fast_tanh(fmaf(fmaf(A[m][1], rs, -mrs), pg.y, pt.y));   \
            A[m][2] = fast_tanh(fmaf(fmaf(A[m][2], rs, -mrs), pg.z, pt.z));   \
            A[m][3] = fast_tanh(fmaf(fmaf(A[m][3], rs, -mrs), pg.w, pt.w));   \
        }                                                                     \
    }

#define H_STORE_T(A)                                                          \
    _Pragma("unroll")                                                         \
    for (int m = 0; m < 4; ++m) {                                             \
        uint2 u;                                                              \
        u.x = pkbf(A[m][0], A[m][1]);                                         \
        u.y = pkbf(A[m][2], A[m][3]);                                         \
        *reinterpret_cast<uint2*>(hwv + cl * 72 + m * 16 + kg4) = u;          \
    }

template<bool PREBF>
__global__ __launch_bounds__(BLOCK, 1) void edge_mlp_t(
    const void* __restrict__ xsrc, const int* __restrict__ ei,
    const float* __restrict__ W1, const float* __restrict__ b1,
    const float* __restrict__ g1, const float* __restrict__ bt1,
    const float* __restrict__ W2, const float* __restrict__ b2,
    const float* __restrict__ g2, const float* __restrict__ bt2,
    const float* __restrict__ W3, const float* __restrict__ b3,
    const float* __restrict__ g3, const float* __restrict__ bt3,
    const float* __restrict__ W4, const float* __restrict__ b4,
    float* __restrict__ out, int E)
{
    __shared__ unsigned short wlds[32 * 512];          // 32 KiB W^T frags
    __shared__ unsigned short hlds[8 * 16 * 72];       // per-wave [16 edge][72] bf16
    __shared__ float plds[10 * 64];                    // b,g,bt x3 + W4

    const int tid  = threadIdx.x;
    const int widx = tid >> 6;
    const int lane = tid & 63;
    const int kg   = lane >> 4;   // 0..3
    const int cl   = lane & 15;   // 0..15 = edge within tile
    const int kg4  = kg * 4;

    for (int fi = widx; fi < 32; fi += 8) {
        const float* Wsrc; int m, kb;
        if (fi < 16) { Wsrc = W1; m = fi >> 2; kb = fi & 3; }
        else { int f = fi - 16; Wsrc = (f < 8) ? W2 : W3; f &= 7; m = f >> 1; kb = f & 1; }
        const float* src = Wsrc + (kb * 32 + kg * 8) * 64 + m * 16 + cl;
        short8 pk8;
        #pragma unroll
        for (int j = 0; j < 8; ++j) pk8[j] = (short)f2bf(src[j * 64]);
        *reinterpret_cast<short8*>(&wlds[fi * 512 + lane * 8]) = pk8;
    }
    for (int i = tid; i < 640; i += BLOCK) {   // grid-stride: BLOCK < 640
        const int p = i >> 6, c = i & 63;
        const float* sp;
        switch (p) {
            case 0: sp = b1;  break; case 1: sp = g1;  break; case 2: sp = bt1; break;
            case 3: sp = b2;  break; case 4: sp = g2;  break; case 5: sp = bt2; break;
            case 6: sp = b3;  break; case 7: sp = g3;  break; case 8: sp = bt3; break;
            default: sp = W4; break;
        }
        plds[i] = sp[c];
    }
    const float b4s = b4[0];
    __syncthreads();

    const unsigned short* xb = (const unsigned short*)xsrc;
    const float*          xf = (const float*)xsrc;
    unsigned short* hwv = hlds + widx * (16 * 72);

    const int ntiles = (E + 15) >> 4;
    const int NW = (int)gridDim.x * 8;

    int t = (int)blockIdx.x * 8 + widx;
    int ns, ne;
    {   // indices for first tile
        const int tc = min(t, ntiles - 1);
        const int er = min((tc << 4) + cl, E - 1);
        ns = ei[er]; ne = ei[E + er];
    }

    for (; t < ntiles; t += NW) {
        // ---- prefetch next tile's indices (consumed at loop bottom) ----
        int nns, nne;
        {
            const int tc = min(t + NW, ntiles - 1);
            const int er = min((tc << 4) + cl, E - 1);
            nns = ei[er]; nne = ei[E + er];
        }

        // ---- issue all 8 gather loads (32-bit offsets) ----
        short8 xa[4];
        float4 u[8];
        #pragma unroll
        for (int kb = 0; kb < 4; ++kb) {
            const unsigned off = (unsigned)(kb < 2 ? ns : ne) * 64u
                               + (unsigned)((kb & 1) * 32 + kg * 8);
            if constexpr (PREBF) {
                xa[kb] = *reinterpret_cast<const short8*>(xb + off);
            } else {
                u[2 * kb]     = *reinterpret_cast<const float4*>(xf + off);
                u[2 * kb + 1] = *reinterpret_cast<const float4*>(xf + off + 4);
            }
        }

        // ---------- Layer 1: per-kb convert + MFMA ----------
        f32x4 acc[4] = {{0,0,0,0},{0,0,0,0},{0,0,0,0},{0,0,0,0}};
        #pragma unroll
        for (int kb = 0; kb < 4; ++kb) {
            short8 af;
            if constexpr (PREBF) {
                af = xa[kb];
            } else {
                uint4 tp_;
                tp_.x = pkbf(u[2 * kb].x,     u[2 * kb].y);
                tp_.y = pkbf(u[2 * kb].z,     u[2 * kb].w);
                tp_.z = pkbf(u[2 * kb + 1].x, u[2 * kb + 1].y);
                tp_.w = pkbf(u[2 * kb + 1].z, u[2 * kb + 1].w);
                af = __builtin_bit_cast(short8, tp_);
            }
            #pragma unroll
            for (int m = 0; m < 4; ++m) {
                const short8 wf = *reinterpret_cast<const short8*>(
                    &wlds[(m * 4 + kb) * 512 + lane * 8]);
                acc[m] = __builtin_amdgcn_mfma_f32_16x16x32_bf16(wf, af, acc[m], 0, 0, 0);
            }
        }
        LN_T(0, 1, 2, acc);
        H_STORE_T(acc);

        // ---------- Layer 2 ----------
        f32x4 acc2[4] = {{0,0,0,0},{0,0,0,0},{0,0,0,0},{0,0,0,0}};
        #pragma unroll
        for (int kb = 0; kb < 2; ++kb) {
            const short8 hf = *reinterpret_cast<const short8*>(
                hwv + cl * 72 + kb * 32 + kg * 8);
            #pragma unroll
            for (int m = 0; m < 4; ++m) {
                const short8 wf = *reinterpret_cast<const short8*>(
                    &wlds[(16 + m * 2 + kb) * 512 + lane * 8]);
                acc2[m] = __builtin_amdgcn_mfma_f32_16x16x32_bf16(wf, hf, acc2[m], 0, 0, 0);
            }
        }
        LN_T(3, 4, 5, acc2);
        H_STORE_T(acc2);

        // ---------- Layer 3 ----------
        f32x4 acc3[4] = {{0,0,0,0},{0,0,0,0},{0,0,0,0},{0,0,0,0}};
        #pragma unroll
        for (int kb = 0; kb < 2; ++kb) {
            const short8 hf = *reinterpret_cast<const short8*>(
                hwv + cl * 72 + kb * 32 + kg * 8);
            #pragma unroll
            for (int m = 0; m < 4; ++m) {
                const short8 wf = *reinterpret_cast<const short8*>(
                    &wlds[(24 + m * 2 + kb) * 512 + lane * 8]);
                acc3[m] = __builtin_amdgcn_mfma_f32_16x16x32_bf16(wf, hf, acc3[m], 0, 0, 0);
            }
        }
        LN_T(6, 7, 8, acc3);

        // ---------- Layer 4: in-lane dot + kg-reduce + sigmoid ----------
        float p = 0.f;
        #pragma unroll
        for (int m = 0; m < 4; ++m) {
            const float4 w4 = *reinterpret_cast<const float4*>(
                plds + 9 * 64 + m * 16 + kg4);
            p = fmaf(acc3[m][0], w4.x, p); p = fmaf(acc3[m][1], w4.y, p);
            p = fmaf(acc3[m][2], w4.z, p); p = fmaf(acc3[m][3], w4.w, p);
        }
        p += __shfl_xor(p, 16); p += __shfl_xor(p, 32);
        if (kg == 0) {
            const int e = (t << 4) + cl;
            if (e < E) {
                const float o = p + b4s;
                out[e] = __builtin_amdgcn_rcpf(
                    1.0f + __builtin_amdgcn_exp2f(o * -1.4426950408889634f));
            }
        }

        ns = nns; ne = nne;
    }
}

__global__ __launch_bounds__(256) void cvt_x_bf16(const float* __restrict__ x,
                                                  unsigned short* __restrict__ xbf,
                                                  int n) {
    const int i = (blockIdx.x * 256 + threadIdx.x) * 8;
    if (i >= n) return;
    const float4 u0 = *reinterpret_cast<const float4*>(x + i);
    const float4 u1 = *reinterpret_cast<const float4*>(x + i + 4);
    uint4 t;
    t.x = pkbf(u0.x, u0.y); t.y = pkbf(u0.z, u0.w);
    t.z = pkbf(u1.x, u1.y); t.w = pkbf(u1.z, u1.w);
    *reinterpret_cast<uint4*>(xbf + i) = t;
}

extern "C" void kernel_launch(void* const* d_in, const int* in_sizes, int n_in,
                              void* d_out, int out_size, void* d_ws, size_t ws_size,
                              hipStream_t stream) {
    const float* x   = (const float*)d_in[0];
    const int*   ei  = (const int*)  d_in[1];
    const float* W1  = (const float*)d_in[2];
    const float* b1  = (const float*)d_in[3];
    const float* g1  = (const float*)d_in[4];
    const float* bt1 = (const float*)d_in[5];
    const float* W2  = (const float*)d_in[6];
    const float* b2  = (const float*)d_in[7];
    const float* g2  = (const float*)d_in[8];
    const float* bt2 = (const float*)d_in[9];
    const float* W3  = (const float*)d_in[10];
    const float* b3  = (const float*)d_in[11];
    const float* g3  = (const float*)d_in[12];
    const float* bt3 = (const float*)d_in[13];
    const float* W4  = (const float*)d_in[14];
    const float* b4  = (const float*)d_in[15];
    float* out = (float*)d_out;

    const int E  = in_sizes[1] / 2;
    const int nX = in_sizes[0];                 // n_nodes * 64

    const bool prebf = (ws_size >= (size_t)nX * 2);

    // grid = CUs x resident blocks/CU (pure occupancy query; capture-safe)
    int nb = 1;
    if (prebf)
        hipOccupancyMaxActiveBlocksPerMultiprocessor(&nb, (const void*)edge_mlp_t<true>,  BLOCK, 0);
    else
        hipOccupancyMaxActiveBlocksPerMultiprocessor(&nb, (const void*)edge_mlp_t<false>, BLOCK, 0);
    if (nb < 1) nb = 1;
    if (nb > 4) nb = 4;
    const int grid = 256 * nb;

    if (prebf) {
        unsigned short* xbf = (unsigned short*)d_ws;
        const int grid_c = (nX / 8 + 255) / 256;
        hipLaunchKernelGGL(cvt_x_bf16, dim3(grid_c), dim3(256), 0, stream, x, xbf, nX);
        hipLaunchKernelGGL((edge_mlp_t<true>), dim3(grid), dim3(BLOCK), 0, stream,
                           (const void*)xbf, ei, W1, b1, g1, bt1, W2, b2, g2, bt2,
                           W3, b3, g3, bt3, W4, b4, out, E);
    } else {
        hipLaunchKernelGGL((edge_mlp_t<false>), dim3(grid), dim3(BLOCK), 0, stream,
                           (const void*)x, ei, W1, b1, g1, bt1, W2, b2, g2, bt2,
                           W3, b3, g3, bt3, W4, b4, out, E);
    }
}

// Round 7
// 114.999 us; speedup vs baseline: 1.2555x; 1.0420x over previous
//
#include <hip/hip_runtime.h>

#define BLOCK 512   // 8 waves

typedef __attribute__((ext_vector_type(8))) short short8;   // 8 x bf16
typedef __attribute__((ext_vector_type(4))) float f32x4;    // MFMA C/D frag

#define TWOLOG2E  2.8853900817779268f   // 2*log2(e), folded into g/beta
#define NLOG2E   -1.4426950408889634f   // -log2(e), folded into W4/b4

__device__ __forceinline__ unsigned short f2bf(float f) {
    unsigned u = __builtin_bit_cast(unsigned, f);
    u += 0x7FFFu + ((u >> 16) & 1u);
    return (unsigned short)(u >> 16);
}

__device__ __forceinline__ unsigned pkbf(float lo, float hi) {
    // dst[15:0]=bf16(lo), dst[31:16]=bf16(hi), RNE
    unsigned r;
    asm("v_cvt_pk_bf16_f32 %0, %1, %2" : "=v"(r) : "v"(lo), "v"(hi));
    return r;
}

// tanh(v*g+bt) with pre-scaled z = v*g' + bt' (g' = 2log2e*g):
// tanh = 1 - 2*rcp(1 + exp2(z)); exact at +-inf
__device__ __forceinline__ float tanh_z(float z) {
    float e = __builtin_amdgcn_exp2f(z);
    return fmaf(-2.0f, __builtin_amdgcn_rcpf(1.0f + e), 1.0f);
}

// LayerNorm + tanh, transposed layout: lane holds edge `cl`, h-cols m*16+kg*4+i.
// pg/pt slots hold g*2log2e, bt*2log2e (folded at staging).
#define LN_T(PB, PG, PT, A)                                                   \
    {                                                                         \
        float s = 0.f, q = 0.f;                                               \
        _Pragma("unroll")                                                     \
        for (int m = 0; m < 4; ++m) {                                         \
            const float4 pb = *reinterpret_cast<const float4*>(               \
                plds + (PB) * 64 + m * 16 + kg4);                             \
            A[m][0] += pb.x; A[m][1] += pb.y;                                 \
            A[m][2] += pb.z; A[m][3] += pb.w;                                 \
            s += (A[m][0] + A[m][1]) + (A[m][2] + A[m][3]);                   \
            q = fmaf(A[m][0], A[m][0], q); q = fmaf(A[m][1], A[m][1], q);     \
            q = fmaf(A[m][2], A[m][2], q); q = fmaf(A[m][3], A[m][3], q);     \
        }                                                                     \
        s += __shfl_xor(s, 16); s += __shfl_xor(s, 32);                       \
        q += __shfl_xor(q, 16); q += __shfl_xor(q, 32);                       \
        const float mu = s * 0.015625f;                                       \
        float var = fmaf(q, 0.015625f, -mu * mu);                             \
        var = fmaxf(var, 0.0f);                                               \
        const float rs = __builtin_amdgcn_rsqf(var + 1e-5f);                  \
        const float mrs = mu * rs;                                            \
        _Pragma("unroll")                                                     \
        for (int m = 0; m < 4; ++m) {                                         \
            const float4 pg = *reinterpret_cast<const float4*>(               \
                plds + (PG) * 64 + m * 16 + kg4);                             \
            const float4 pt = *reinterpret_cast<const float4*>(               \
                plds + (PT) * 64 + m * 16 + kg4);                             \
            A[m][0] = tanh_z(fmaf(fmaf(A[m][0], rs, -mrs), pg.x, pt.x));      \
            A[m][1] = tanh_z(fmaf(fmaf(A[m][1], rs, -mrs), pg.y, pt.y));      \
            A[m][2] = tanh_z(fmaf(fmaf(A[m][2], rs, -mrs), pg.z, pt.z));      \
            A[m][3] = tanh_z(fmaf(fmaf(A[m][3], rs, -mrs), pg.w, pt.w));      \
        }                                                                     \
    }

#define H_STORE_T(A)                                                          \
    _Pragma("unroll")                                                         \
    for (int m = 0; m < 4; ++m) {                                             \
        uint2 u2;                                                             \
        u2.x = pkbf(A[m][0], A[m][1]);                                        \
        u2.y = pkbf(A[m][2], A[m][3]);                                        \
        *reinterpret_cast<uint2*>(hwv + cl * 72 + m * 16 + kg4) = u2;         \
    }

// issue the 8 x-gather loads (f32 path) or 4 bf16 loads for a tile
#define GATHER(NS, NE)                                                        \
    _Pragma("unroll")                                                         \
    for (int kb = 0; kb < 4; ++kb) {                                          \
        const unsigned off = (unsigned)(kb < 2 ? (NS) : (NE)) * 64u           \
                           + (unsigned)((kb & 1) * 32 + kg * 8);              \
        if constexpr (PREBF) {                                                \
            xa[kb] = *reinterpret_cast<const short8*>(xb + off);              \
        } else {                                                              \
            u[2 * kb]     = *reinterpret_cast<const float4*>(xf + off);       \
            u[2 * kb + 1] = *reinterpret_cast<const float4*>(xf + off + 4);   \
        }                                                                     \
    }

#define LDIDX(T, A_, B_)                                                      \
    {                                                                         \
        const int tc_ = min((T), ntiles - 1);                                 \
        const int er_ = min((tc_ << 4) + cl, E - 1);                          \
        A_ = ei[er_]; B_ = ei[E + er_];                                       \
    }

template<bool PREBF>
__global__ __launch_bounds__(BLOCK) void edge_mlp_t(
    const void* __restrict__ xsrc, const int* __restrict__ ei,
    const float* __restrict__ W1, const float* __restrict__ b1,
    const float* __restrict__ g1, const float* __restrict__ bt1,
    const float* __restrict__ W2, const float* __restrict__ b2,
    const float* __restrict__ g2, const float* __restrict__ bt2,
    const float* __restrict__ W3, const float* __restrict__ b3,
    const float* __restrict__ g3, const float* __restrict__ bt3,
    const float* __restrict__ W4, const float* __restrict__ b4,
    float* __restrict__ out, int E)
{
    __shared__ unsigned short wlds[32 * 512];          // 32 KiB W^T frags
    __shared__ unsigned short hlds[8 * 16 * 72];       // per-wave [16 edge][72] bf16
    __shared__ float plds[10 * 64];                    // b,g',bt' x3 + W4'

    const int tid  = threadIdx.x;
    const int widx = tid >> 6;
    const int lane = tid & 63;
    const int kg   = lane >> 4;   // 0..3
    const int cl   = lane & 15;   // 0..15 = edge within tile
    const int kg4  = kg * 4;

    for (int fi = widx; fi < 32; fi += 8) {
        const float* Wsrc; int m, kb;
        if (fi < 16) { Wsrc = W1; m = fi >> 2; kb = fi & 3; }
        else { int f = fi - 16; Wsrc = (f < 8) ? W2 : W3; f &= 7; m = f >> 1; kb = f & 1; }
        const float* src = Wsrc + (kb * 32 + kg * 8) * 64 + m * 16 + cl;
        short8 pk8;
        #pragma unroll
        for (int j = 0; j < 8; ++j) pk8[j] = (short)f2bf(src[j * 64]);
        *reinterpret_cast<short8*>(&wlds[fi * 512 + lane * 8]) = pk8;
    }
    // params -> LDS with constant folding: g,bt scaled by 2log2e; W4 by -log2e
    for (int i = tid; i < 640; i += BLOCK) {
        const int p = i >> 6, c = i & 63;
        const float* sp; float sc;
        switch (p) {
            case 0: sp = b1;  sc = 1.0f;     break;
            case 1: sp = g1;  sc = TWOLOG2E; break;
            case 2: sp = bt1; sc = TWOLOG2E; break;
            case 3: sp = b2;  sc = 1.0f;     break;
            case 4: sp = g2;  sc = TWOLOG2E; break;
            case 5: sp = bt2; sc = TWOLOG2E; break;
            case 6: sp = b3;  sc = 1.0f;     break;
            case 7: sp = g3;  sc = TWOLOG2E; break;
            case 8: sp = bt3; sc = TWOLOG2E; break;
            default: sp = W4; sc = NLOG2E;   break;
        }
        plds[i] = sp[c] * sc;
    }
    const float b4s = b4[0] * NLOG2E;
    __syncthreads();

    const unsigned short* xb = (const unsigned short*)xsrc;
    const float*          xf = (const float*)xsrc;
    unsigned short* hwv = hlds + widx * (16 * 72);

    const int ntiles = (E + 15) >> 4;
    const int NW = (int)gridDim.x * 8;

    int t = (int)blockIdx.x * 8 + widx;

    // ---- 2-deep pipeline state: x data of tile t, indices of tile t+NW ----
    float4 u[8];
    short8 xa[4];
    int ns1, ne1;
    {
        int ns0, ne0;
        LDIDX(t, ns0, ne0);
        GATHER(ns0, ne0);
        LDIDX(t + NW, ns1, ne1);
    }

    for (; t < ntiles; t += NW) {
        // ---- consume this tile's x (in flight since last iteration) ----
        short8 af[4];
        if constexpr (PREBF) {
            #pragma unroll
            for (int kb = 0; kb < 4; ++kb) af[kb] = xa[kb];
        } else {
            #pragma unroll
            for (int kb = 0; kb < 4; ++kb) {
                uint4 tp_;
                tp_.x = pkbf(u[2 * kb].x,     u[2 * kb].y);
                tp_.y = pkbf(u[2 * kb].z,     u[2 * kb].w);
                tp_.z = pkbf(u[2 * kb + 1].x, u[2 * kb + 1].y);
                tp_.w = pkbf(u[2 * kb + 1].z, u[2 * kb + 1].w);
                af[kb] = __builtin_bit_cast(short8, tp_);
            }
        }

        // ---- immediately re-issue: next tile's x + next-next indices ----
        GATHER(ns1, ne1);
        LDIDX(t + 2 * NW, ns1, ne1);

        // ---------- Layer 1 ----------
        f32x4 acc[4] = {{0,0,0,0},{0,0,0,0},{0,0,0,0},{0,0,0,0}};
        #pragma unroll
        for (int kb = 0; kb < 4; ++kb) {
            #pragma unroll
            for (int m = 0; m < 4; ++m) {
                const short8 wf = *reinterpret_cast<const short8*>(
                    &wlds[(m * 4 + kb) * 512 + lane * 8]);
                acc[m] = __builtin_amdgcn_mfma_f32_16x16x32_bf16(wf, af[kb], acc[m], 0, 0, 0);
            }
        }
        LN_T(0, 1, 2, acc);
        H_STORE_T(acc);

        // ---------- Layer 2 ----------
        f32x4 acc2[4] = {{0,0,0,0},{0,0,0,0},{0,0,0,0},{0,0,0,0}};
        #pragma unroll
        for (int kb = 0; kb < 2; ++kb) {
            const short8 hf = *reinterpret_cast<const short8*>(
                hwv + cl * 72 + kb * 32 + kg * 8);
            #pragma unroll
            for (int m = 0; m < 4; ++m) {
                const short8 wf = *reinterpret_cast<const short8*>(
                    &wlds[(16 + m * 2 + kb) * 512 + lane * 8]);
                acc2[m] = __builtin_amdgcn_mfma_f32_16x16x32_bf16(wf, hf, acc2[m], 0, 0, 0);
            }
        }
        LN_T(3, 4, 5, acc2);
        H_STORE_T(acc2);

        // ---------- Layer 3 ----------
        f32x4 acc3[4] = {{0,0,0,0},{0,0,0,0},{0,0,0,0},{0,0,0,0}};
        #pragma unroll
        for (int kb = 0; kb < 2; ++kb) {
            const short8 hf = *reinterpret_cast<const short8*>(
                hwv + cl * 72 + kb * 32 + kg * 8);
            #pragma unroll
            for (int m = 0; m < 4; ++m) {
                const short8 wf = *reinterpret_cast<const short8*>(
                    &wlds[(24 + m * 2 + kb) * 512 + lane * 8]);
                acc3[m] = __builtin_amdgcn_mfma_f32_16x16x32_bf16(wf, hf, acc3[m], 0, 0, 0);
            }
        }
        LN_T(6, 7, 8, acc3);

        // ---------- Layer 4: in-lane dot (W4 pre-scaled) + sigmoid ----------
        float p = 0.f;
        #pragma unroll
        for (int m = 0; m < 4; ++m) {
            const float4 w4 = *reinterpret_cast<const float4*>(
                plds + 9 * 64 + m * 16 + kg4);
            p = fmaf(acc3[m][0], w4.x, p); p = fmaf(acc3[m][1], w4.y, p);
            p = fmaf(acc3[m][2], w4.z, p); p = fmaf(acc3[m][3], w4.w, p);
        }
        p += __shfl_xor(p, 16); p += __shfl_xor(p, 32);
        if (kg == 0) {
            const int e = (t << 4) + cl;
            if (e < E) {
                // p already = -log2(e) * (h.W4 + b4)
                out[e] = __builtin_amdgcn_rcpf(
                    1.0f + __builtin_amdgcn_exp2f(p + b4s));
            }
        }
    }
}

__global__ __launch_bounds__(256) void cvt_x_bf16(const float* __restrict__ x,
                                                  unsigned short* __restrict__ xbf,
                                                  int n) {
    const int i = (blockIdx.x * 256 + threadIdx.x) * 8;
    if (i >= n) return;
    const float4 u0 = *reinterpret_cast<const float4*>(x + i);
    const float4 u1 = *reinterpret_cast<const float4*>(x + i + 4);
    uint4 t;
    t.x = pkbf(u0.x, u0.y); t.y = pkbf(u0.z, u0.w);
    t.z = pkbf(u1.x, u1.y); t.w = pkbf(u1.z, u1.w);
    *reinterpret_cast<uint4*>(xbf + i) = t;
}

extern "C" void kernel_launch(void* const* d_in, const int* in_sizes, int n_in,
                              void* d_out, int out_size, void* d_ws, size_t ws_size,
                              hipStream_t stream) {
    const float* x   = (const float*)d_in[0];
    const int*   ei  = (const int*)  d_in[1];
    const float* W1  = (const float*)d_in[2];
    const float* b1  = (const float*)d_in[3];
    const float* g1  = (const float*)d_in[4];
    const float* bt1 = (const float*)d_in[5];
    const float* W2  = (const float*)d_in[6];
    const float* b2  = (const float*)d_in[7];
    const float* g2  = (const float*)d_in[8];
    const float* bt2 = (const float*)d_in[9];
    const float* W3  = (const float*)d_in[10];
    const float* b3  = (const float*)d_in[11];
    const float* g3  = (const float*)d_in[12];
    const float* bt3 = (const float*)d_in[13];
    const float* W4  = (const float*)d_in[14];
    const float* b4  = (const float*)d_in[15];
    float* out = (float*)d_out;

    const int E  = in_sizes[1] / 2;
    const int nX = in_sizes[0];                 // n_nodes * 64

    const bool prebf = (ws_size >= (size_t)nX * 2);

    int nb = 1;
    if (prebf)
        hipOccupancyMaxActiveBlocksPerMultiprocessor(&nb, (const void*)edge_mlp_t<true>,  BLOCK, 0);
    else
        hipOccupancyMaxActiveBlocksPerMultiprocessor(&nb, (const void*)edge_mlp_t<false>, BLOCK, 0);
    if (nb < 1) nb = 1;
    if (nb > 4) nb = 4;
    const int grid = 256 * nb;

    if (prebf) {
        unsigned short* xbf = (unsigned short*)d_ws;
        const int grid_c = (nX / 8 + 255) / 256;
        hipLaunchKernelGGL(cvt_x_bf16, dim3(grid_c), dim3(256), 0, stream, x, xbf, nX);
        hipLaunchKernelGGL((edge_mlp_t<true>), dim3(grid), dim3(BLOCK), 0, stream,
                           (const void*)xbf, ei, W1, b1, g1, bt1, W2, b2, g2, bt2,
                           W3, b3, g3, bt3, W4, b4, out, E);
    } else {
        hipLaunchKernelGGL((edge_mlp_t<false>), dim3(grid), dim3(BLOCK), 0, stream,
                           (const void*)x, ei, W1, b1, g1, bt1, W2, b2, g2, bt2,
                           W3, b3, g3, bt3, W4, b4, out, E);
    }
}